// Round 1
// baseline (4774.246 us; speedup 1.0000x reference)
//
#include <hip/hip_runtime.h>
#include <hip/hip_cooperative_groups.h>
#include <cmath>

namespace cg = cooperative_groups;

#define T_  128
#define B_  128
#define I_  256
#define H_  256
#define G4_ 1024

#define ROWS 8
#define COLS 16
#define KC   64
#define XPAD (I_ + 4)   // pad to break bank alignment on row stride
#define WPAD (KC + 4)

// Persistent cooperative LSTM: grid = 256 blocks x 256 threads.
// Block (rt,ct): rows rt*8..+7, cols ct*16..+15 of h/c. blockIdx = rt*16+ct so
// blocks sharing a weight slice (same ct) land on the same XCD (bid%8 == ct%8).
// Threads: p = tid>>7 selects K-half (0: x@Wi, 1: h@Wh); (tr,tc) = output elem.
__global__ __launch_bounds__(256, 1)
void lstm_fused(const float* __restrict__ x,     // [T,B,I]
                const float* __restrict__ h0,    // [B,H]
                const float* __restrict__ c0in,  // [B,H]
                const float* __restrict__ Wi,    // [T,I,4H]
                const float* __restrict__ bi,    // [T,4H]
                const float* __restrict__ Wh,    // [T,H,4H]
                const float* __restrict__ bh,    // [T,4H]
                float* __restrict__ out)         // [T*B*H | B*H | B*H]
{
    cg::grid_group grid = cg::this_grid();

    __shared__ float xs[ROWS][XPAD];
    __shared__ float hs[ROWS][XPAD];
    __shared__ float ws[2][COLS * 4][WPAD];     // [matrix][gate*16+col][k] transposed chunk
    __shared__ float partial[4][ROWS * COLS];

    const int tid = threadIdx.x;
    const int rt  = blockIdx.x >> 4;
    const int ct  = blockIdx.x & 15;
    const int r0  = rt * ROWS;
    const int cb  = ct * COLS;

    const int p   = tid >> 7;         // 0: x-part, 1: h-part
    const int tr  = (tid >> 4) & 7;   // row within tile
    const int tc  = tid & 15;         // col within tile
    const int row = r0 + tr;
    const int col = cb + tc;

    float cst = (p == 1) ? c0in[row * H_ + col] : 0.f;

    float4 regs[2][4];

    for (int t = 0; t < T_; ++t) {
        // ---- stage x_t and h_{t-1} rows (8 x 256 each) ----
        #pragma unroll
        for (int q = 0; q < 2; ++q) {
            const int li = tid + 256 * q;
            const int sr = li >> 6;          // 0..7
            const int sk = (li & 63) * 4;    // 0..252
            *(float4*)&xs[sr][sk] =
                *(const float4*)&x[(t * B_ + r0 + sr) * I_ + sk];
            const float* hsrc = (t == 0)
                ? (h0 + (r0 + sr) * H_ + sk)
                : (out + ((t - 1) * B_ + r0 + sr) * H_ + sk);
            *(float4*)&hs[sr][sk] = *(const float4*)hsrc;
        }

        float acc[4] = {0.f, 0.f, 0.f, 0.f};

        // prefetch weight chunk 0 into registers
        #pragma unroll
        for (int m = 0; m < 2; ++m) {
            const float* Wsrc = m ? Wh : Wi;
            #pragma unroll
            for (int q = 0; q < 4; ++q) {
                const int s  = tid + 256 * q;
                const int kk = s >> 4;
                const int fx = s & 15;
                const int g  = fx >> 2;
                const int c4 = (fx & 3) * 4;
                regs[m][q] = *(const float4*)&Wsrc[(t * 256 + kk) * G4_ + cb + g * 256 + c4];
            }
        }

        for (int ch = 0; ch < 4; ++ch) {
            __syncthreads();   // ws free (prev chunk compute / prev step done)

            // commit prefetched chunk to LDS (transposed: [col][k])
            #pragma unroll
            for (int m = 0; m < 2; ++m) {
                #pragma unroll
                for (int q = 0; q < 4; ++q) {
                    const int s  = tid + 256 * q;
                    const int kk = s >> 4;
                    const int fx = s & 15;
                    const int g  = fx >> 2;
                    const int c4 = (fx & 3) * 4;
                    const float4 v = regs[m][q];
                    ws[m][g * 16 + c4 + 0][kk] = v.x;
                    ws[m][g * 16 + c4 + 1][kk] = v.y;
                    ws[m][g * 16 + c4 + 2][kk] = v.z;
                    ws[m][g * 16 + c4 + 3][kk] = v.w;
                }
            }

            // issue next chunk's global loads (latency hides under compute)
            if (ch < 3) {
                #pragma unroll
                for (int m = 0; m < 2; ++m) {
                    const float* Wsrc = m ? Wh : Wi;
                    #pragma unroll
                    for (int q = 0; q < 4; ++q) {
                        const int s  = tid + 256 * q;
                        const int kk = s >> 4;
                        const int fx = s & 15;
                        const int g  = fx >> 2;
                        const int c4 = (fx & 3) * 4;
                        regs[m][q] = *(const float4*)
                            &Wsrc[(t * 256 + (ch + 1) * KC + kk) * G4_ + cb + g * 256 + c4];
                    }
                }
            }

            __syncthreads();

            // compute this chunk: acc[g] += sum_k src[tr][k] * ws[p][g*16+tc][k]
            const float(*src)[XPAD] = p ? hs : xs;
            #pragma unroll
            for (int k4 = 0; k4 < KC / 4; ++k4) {
                const float4 v = *(const float4*)&src[tr][ch * KC + k4 * 4];
                #pragma unroll
                for (int g = 0; g < 4; ++g) {
                    const float4 w = *(const float4*)&ws[p][g * 16 + tc][k4 * 4];
                    acc[g] += v.x * w.x + v.y * w.y + v.z * w.z + v.w * w.w;
                }
            }
        }

        __syncthreads();
        if (p == 0) {
            partial[0][tr * 16 + tc] = acc[0];
            partial[1][tr * 16 + tc] = acc[1];
            partial[2][tr * 16 + tc] = acc[2];
            partial[3][tr * 16 + tc] = acc[3];
        }
        __syncthreads();

        if (p == 1) {
            const int bidx = t * G4_ + col;   // + g*256 per gate
            const float gi = acc[0] + partial[0][tr * 16 + tc] + bi[bidx + 0 * 256] + bh[bidx + 0 * 256];
            const float gf = acc[1] + partial[1][tr * 16 + tc] + bi[bidx + 1 * 256] + bh[bidx + 1 * 256];
            const float go = acc[2] + partial[2][tr * 16 + tc] + bi[bidx + 2 * 256] + bh[bidx + 2 * 256];
            const float gg = acc[3] + partial[3][tr * 16 + tc] + bi[bidx + 3 * 256] + bh[bidx + 3 * 256];

            const float i_ = 1.f / (1.f + expf(-gi));
            const float f_ = 1.f / (1.f + expf(-gf));
            const float o_ = 1.f / (1.f + expf(-go));
            const float gt = tanhf(gg);
            cst = f_ * cst + i_ * gt;
            const float hv = o_ * tanhf(cst);

            out[(t * B_ + row) * H_ + col] = hv;
            if (t == T_ - 1) {
                out[T_ * B_ * H_ + row * H_ + col] = hv;
                out[T_ * B_ * H_ + B_ * H_ + row * H_ + col] = cst;
            }
        }

        grid.sync();
    }
}

extern "C" void kernel_launch(void* const* d_in, const int* in_sizes, int n_in,
                              void* d_out, int out_size, void* d_ws, size_t ws_size,
                              hipStream_t stream) {
    const float* x  = (const float*)d_in[0];
    const float* h0 = (const float*)d_in[1];
    const float* c0 = (const float*)d_in[2];
    const float* Wi = (const float*)d_in[3];
    const float* bi = (const float*)d_in[4];
    const float* Wh = (const float*)d_in[5];
    const float* bh = (const float*)d_in[6];
    float* out = (float*)d_out;

    void* args[] = {&x, &h0, &c0, &Wi, &bi, &Wh, &bh, &out};
    hipLaunchCooperativeKernel((void*)lstm_fused, dim3(256), dim3(256),
                               args, 0, stream);
}